// Round 6
// baseline (40.181 us; speedup 1.0000x reference)
//
#include <hip/hip_runtime.h>

__device__ __forceinline__ float lrelu(float v) { return v >= 0.f ? v : 0.01f * v; }

__device__ __forceinline__ unsigned long long shfl_down_u64(unsigned long long v, int off) {
    unsigned lo = (unsigned)(v & 0xffffffffu);
    unsigned hi = (unsigned)(v >> 32);
    lo = __shfl_down(lo, off, 64);
    hi = __shfl_down(hi, off, 64);
    return ((unsigned long long)hi << 32) | lo;
}

#define KEY_STRIDE 8   // u64s; one key per 64B cache line to avoid atomic line contention

// ---------------- K1: encode (one 64-thread block per batch) ----------------
__global__ __launch_bounds__(64) void k_encode(
    const float* __restrict__ x, const float* __restrict__ eps,
    const float* __restrict__ w_e0, const float* __restrict__ b_e0,
    const float* __restrict__ w_e1, const float* __restrict__ b_e1,
    const float* __restrict__ w_mu, const float* __restrict__ b_mu,
    const float* __restrict__ w_lv, const float* __restrict__ b_lv,
    float* __restrict__ out, unsigned long long* __restrict__ keys)
{
    const int b   = blockIdx.x;
    const int tid = threadIdx.x;
    __shared__ float h1s[50];

    if (tid == 0) keys[b * KEY_STRIDE] = ~0ull;   // re-init every call (graph replay safe)

    if (tid < 50) {
        const float xv = x[b];
        float acc = b_e1[tid];
        #pragma unroll
        for (int i = 0; i < 10; ++i) {
            float h = lrelu(fmaf(xv, w_e0[i], b_e0[i]));
            acc = fmaf(h, w_e1[i * 50 + tid], acc);
        }
        h1s[tid] = lrelu(acc);
    }
    __syncthreads();

    float mu = b_mu[tid];
    float lv = b_lv[tid];
    for (int i = 0; i < 50; ++i) {
        float h = h1s[i];
        mu = fmaf(h, w_mu[i * 64 + tid], mu);
        lv = fmaf(h, w_lv[i * 64 + tid], lv);
    }
    out[b * 64 + tid] = fmaf(eps[b * 64 + tid], expf(0.5f * lv), mu);   // z_e
}

// ---------------- K2: SOM scan, table-tiled ----------------
// Block g owns rows 16g..16g+15 (4 KB -> 16 VGPR/lane). Stages all z_e (64 KB)
// into LDS. Each wave handles 16 batches; per batch: 16 dists via 2-stage
// shfl_xor, key-min over the wave, one u64 atomicMin per (block, batch).
__global__ __launch_bounds__(1024) void k_scan(
    const float* __restrict__ emb, const float* __restrict__ zE,
    unsigned long long* __restrict__ keys)
{
    const int g    = blockIdx.x;
    const int tid  = threadIdx.x;
    const int wv   = tid >> 6;
    const int lane = tid & 63;

    __shared__ __align__(16) float zs[256 * 64];   // 64 KB

    // stage z_e (coalesced float4)
    {
        const float4* src = reinterpret_cast<const float4*>(zE);
        float4* dst = reinterpret_cast<float4*>(zs);
        #pragma unroll
        for (int i = 0; i < 4; ++i) dst[tid + i * 1024] = src[tid + i * 1024];
    }

    // table fragment: lane covers row g*16+(lane>>2), dims (lane&3)*16..+15
    const int row = g * 16 + (lane >> 2);
    const float* tp = emb + row * 64 + (lane & 3) * 16;
    const float4 e0 = *reinterpret_cast<const float4*>(tp + 0);
    const float4 e1 = *reinterpret_cast<const float4*>(tp + 4);
    const float4 e2 = *reinterpret_cast<const float4*>(tp + 8);
    const float4 e3 = *reinterpret_cast<const float4*>(tp + 12);
    __syncthreads();

    const float* zb = zs + (lane & 3) * 16;
    #pragma unroll 1
    for (int t = 0; t < 16; ++t) {
        const int j = wv * 16 + t;
        const float4 z0 = *reinterpret_cast<const float4*>(zb + j * 64 + 0);
        const float4 z1 = *reinterpret_cast<const float4*>(zb + j * 64 + 4);
        const float4 z2 = *reinterpret_cast<const float4*>(zb + j * 64 + 8);
        const float4 z3 = *reinterpret_cast<const float4*>(zb + j * 64 + 12);
        float p = 0.f, d;
        d = e0.x - z0.x; p = fmaf(d, d, p);
        d = e0.y - z0.y; p = fmaf(d, d, p);
        d = e0.z - z0.z; p = fmaf(d, d, p);
        d = e0.w - z0.w; p = fmaf(d, d, p);
        d = e1.x - z1.x; p = fmaf(d, d, p);
        d = e1.y - z1.y; p = fmaf(d, d, p);
        d = e1.z - z1.z; p = fmaf(d, d, p);
        d = e1.w - z1.w; p = fmaf(d, d, p);
        d = e2.x - z2.x; p = fmaf(d, d, p);
        d = e2.y - z2.y; p = fmaf(d, d, p);
        d = e2.z - z2.z; p = fmaf(d, d, p);
        d = e2.w - z2.w; p = fmaf(d, d, p);
        d = e3.x - z3.x; p = fmaf(d, d, p);
        d = e3.y - z3.y; p = fmaf(d, d, p);
        d = e3.z - z3.z; p = fmaf(d, d, p);
        d = e3.w - z3.w; p = fmaf(d, d, p);
        // full distance onto all 4 lanes of the row group
        p += __shfl_xor(p, 1);
        p += __shfl_xor(p, 2);
        // dist >= 0: float bits order-preserving; low 32 = row ->
        // first-occurrence tie-break like jnp.argmin. min is commutative ->
        // deterministic under any atomic order.
        unsigned long long key =
            ((unsigned long long)__float_as_uint(p) << 32) | (unsigned)row;
        #pragma unroll
        for (int off = 32; off >= 4; off >>= 1) {
            unsigned long long o = shfl_down_u64(key, off);
            key = o < key ? o : key;
        }
        if (lane == 0) atomicMin(&keys[j * KEY_STRIDE], key);
    }
}

// ---------------- K3: neighbors + decode (one 128-thread block per batch) ----------------
__global__ __launch_bounds__(128) void k_finish(
    const float* __restrict__ emb,
    const float* __restrict__ w_d,  const float* __restrict__ b_d,
    const float* __restrict__ w_d0, const float* __restrict__ b_d0,
    const float* __restrict__ w_d1, const float* __restrict__ b_d1,
    const float* __restrict__ w_d2, const float* __restrict__ b_d2,
    const unsigned long long* __restrict__ keys,
    float* __restrict__ out)
{
    const int b    = blockIdx.x;
    const int tid  = threadIdx.x;
    const int wv   = tid >> 6;
    const int lane = tid & 63;

    __shared__ float zbuf[2][64];
    __shared__ float t0s[2][100];
    __shared__ float t1s[2][60];
    __shared__ float t2s[2][30];

    const int nmin = (int)(keys[b * KEY_STRIDE] & 0xffffffffu);
    const int nx = nmin >> 6, ny = nmin & 63;

    if (tid < 64) {
        const int j = tid;
        zbuf[0][j] = out[b * 64 + j];                     // z_e (written by K1)
        float zq = emb[nmin * 64 + j];
        zbuf[1][j] = zq;
        out[16384 + b * 64 + j] = zq;                     // z_q
        const int nb = 32768 + b * 320;                   // z_q_neighbors [B,5,64]
        out[nb + j] = zq;                                 // row 0: z_q
        float up = (nx < 63) ? emb[((nx + 1) * 64 + ny) * 64 + j] : 0.f;
        out[nb + 64 + j] = up;                            // row 1: up
        float dn = (nx > 0) ? emb[((nx - 1) * 64 + ny) * 64 + j] : 0.f;
        out[nb + 128 + j] = dn;                           // row 2: down
        out[nb + 192 + j] = 0.f;                          // row 3: right (faithful bug)
        float lf = (ny > 0) ? emb[(nx * 64 + (ny - 1)) * 64 + j] : 0.f;
        out[nb + 256 + j] = lf;                           // row 4: left
    }
    __syncthreads();

    // decode: wave 0 -> z_e, wave 1 -> z_q
    for (int j = lane; j < 100; j += 64) {
        float acc = b_d[j];
        for (int i = 0; i < 64; ++i)
            acc = fmaf(zbuf[wv][i], w_d[i * 100 + j], acc);
        t0s[wv][j] = lrelu(acc);
    }
    __syncthreads();
    if (lane < 60) {
        float acc = b_d0[lane];
        for (int i = 0; i < 100; ++i)
            acc = fmaf(t0s[wv][i], w_d0[i * 60 + lane], acc);
        t1s[wv][lane] = lrelu(acc);
    }
    __syncthreads();
    if (lane < 30) {
        float acc = b_d1[lane];
        for (int i = 0; i < 60; ++i)
            acc = fmaf(t1s[wv][i], w_d1[i * 30 + lane], acc);
        t2s[wv][lane] = lrelu(acc);
    }
    __syncthreads();
    if (lane == 0) {
        float acc = b_d2[0];
        for (int i = 0; i < 30; ++i)
            acc = fmaf(t2s[wv][i], w_d2[i], acc);
        float r = lrelu(acc);
        out[(wv == 0 ? 114688 : 114944) + b] = r;         // decoder_e / decoder_q
    }
}

extern "C" void kernel_launch(void* const* d_in, const int* in_sizes, int n_in,
                              void* d_out, int out_size, void* d_ws, size_t ws_size,
                              hipStream_t stream) {
    (void)in_sizes; (void)n_in; (void)ws_size; (void)out_size;
    const float* x    = (const float*)d_in[0];
    const float* eps  = (const float*)d_in[1];
    const float* emb  = (const float*)d_in[2];
    const float* w_e0 = (const float*)d_in[3];
    const float* b_e0 = (const float*)d_in[4];
    const float* w_e1 = (const float*)d_in[5];
    const float* b_e1 = (const float*)d_in[6];
    const float* w_mu = (const float*)d_in[7];
    const float* b_mu = (const float*)d_in[8];
    const float* w_lv = (const float*)d_in[9];
    const float* b_lv = (const float*)d_in[10];
    const float* w_d  = (const float*)d_in[11];
    const float* b_d  = (const float*)d_in[12];
    const float* w_d0 = (const float*)d_in[13];
    const float* b_d0 = (const float*)d_in[14];
    const float* w_d1 = (const float*)d_in[15];
    const float* b_d1 = (const float*)d_in[16];
    const float* w_d2 = (const float*)d_in[17];
    const float* b_d2 = (const float*)d_in[18];
    float* out = (float*)d_out;
    unsigned long long* keys = (unsigned long long*)d_ws;

    k_encode<<<256, 64, 0, stream>>>(x, eps, w_e0, b_e0, w_e1, b_e1,
                                     w_mu, b_mu, w_lv, b_lv, out, keys);
    k_scan<<<256, 1024, 0, stream>>>(emb, out, keys);
    k_finish<<<256, 128, 0, stream>>>(emb, w_d, b_d, w_d0, b_d0,
                                      w_d1, b_d1, w_d2, b_d2, keys, out);
}

// Round 7
// 35.713 us; speedup vs baseline: 1.1251x; 1.1251x over previous
//
#include <hip/hip_runtime.h>

__device__ __forceinline__ float lrelu(float v) { return v >= 0.f ? v : 0.01f * v; }

__device__ __forceinline__ unsigned long long shfl_down_u64(unsigned long long v, int off, int width) {
    unsigned lo = (unsigned)(v & 0xffffffffu);
    unsigned hi = (unsigned)(v >> 32);
    lo = __shfl_down(lo, off, width);
    hi = __shfl_down(hi, off, width);
    return ((unsigned long long)hi << 32) | lo;
}

// ---------------- K1: fused encode + table-tiled SOM scan ----------------
// Grid 256 = 16 batch-tiles x 16 row-tiles. Block (bt, rt):
//   - each of 16 waves encodes one batch j = bt*16+wv (z_e -> LDS; rt==0 writes out)
//   - lane holds row rt*256 + wv*16 + (lane>>2), dims (lane&3)*16..+15 (16 VGPRs)
//   - per batch t: 16 FMA + shfl_xor(1,2) -> full dist on row quad; key-min over
//     wave's 16 rows via shfl_down; wave lane0 -> cand[t][wv]
//   - block reduce: 16 lanes per batch min 16 wave-candidates -> ws[batch*16+rt]
// No atomics: every ws slot written exactly once per call (deterministic).
__global__ __launch_bounds__(1024) void k_scan_enc(
    const float* __restrict__ x, const float* __restrict__ eps,
    const float* __restrict__ emb,
    const float* __restrict__ w_e0, const float* __restrict__ b_e0,
    const float* __restrict__ w_e1, const float* __restrict__ b_e1,
    const float* __restrict__ w_mu, const float* __restrict__ b_mu,
    const float* __restrict__ w_lv, const float* __restrict__ b_lv,
    float* __restrict__ out, unsigned long long* __restrict__ ws)
{
    const int bt   = blockIdx.x >> 4;
    const int rt   = blockIdx.x & 15;
    const int tid  = threadIdx.x;
    const int wv   = tid >> 6;
    const int lane = tid & 63;

    __shared__ float h1s[16][52];
    __shared__ __align__(16) float zs[16][64];
    __shared__ unsigned long long cand[16][16];   // [batch][wave-slot]

    // ---- encode batch j = bt*16 + wv (wave-private; same f32 ops in every
    //      rt block -> bit-identical z) ----
    const int j = bt * 16 + wv;
    if (lane < 50) {
        const float xv = x[j];
        float acc = b_e1[lane];
        #pragma unroll
        for (int i = 0; i < 10; ++i) {
            float h = lrelu(fmaf(xv, w_e0[i], b_e0[i]));
            acc = fmaf(h, w_e1[i * 50 + lane], acc);
        }
        h1s[wv][lane] = lrelu(acc);               // wave-private LDS, no barrier needed
    }
    {
        float mu = b_mu[lane];
        float lv = b_lv[lane];
        for (int i = 0; i < 50; ++i) {
            float h = h1s[wv][i];
            mu = fmaf(h, w_mu[i * 64 + lane], mu);
            lv = fmaf(h, w_lv[i * 64 + lane], lv);
        }
        float z = fmaf(eps[j * 64 + lane], expf(0.5f * lv), mu);
        zs[wv][lane] = z;
        if (rt == 0) out[j * 64 + lane] = z;      // z_e written exactly once per batch
    }
    __syncthreads();                              // zs read cross-wave below

    // ---- table fragment: 16 floats/lane in registers ----
    const int row = rt * 256 + wv * 16 + (lane >> 2);
    const float* tp = emb + row * 64 + (lane & 3) * 16;
    const float4 e0 = *reinterpret_cast<const float4*>(tp + 0);
    const float4 e1 = *reinterpret_cast<const float4*>(tp + 4);
    const float4 e2 = *reinterpret_cast<const float4*>(tp + 8);
    const float4 e3 = *reinterpret_cast<const float4*>(tp + 12);

    #pragma unroll 1
    for (int t = 0; t < 16; ++t) {
        const float* zb = &zs[t][(lane & 3) * 16];
        const float4 z0 = *reinterpret_cast<const float4*>(zb + 0);
        const float4 z1 = *reinterpret_cast<const float4*>(zb + 4);
        const float4 z2 = *reinterpret_cast<const float4*>(zb + 8);
        const float4 z3 = *reinterpret_cast<const float4*>(zb + 12);
        float p = 0.f, d;
        d = e0.x - z0.x; p = fmaf(d, d, p);
        d = e0.y - z0.y; p = fmaf(d, d, p);
        d = e0.z - z0.z; p = fmaf(d, d, p);
        d = e0.w - z0.w; p = fmaf(d, d, p);
        d = e1.x - z1.x; p = fmaf(d, d, p);
        d = e1.y - z1.y; p = fmaf(d, d, p);
        d = e1.z - z1.z; p = fmaf(d, d, p);
        d = e1.w - z1.w; p = fmaf(d, d, p);
        d = e2.x - z2.x; p = fmaf(d, d, p);
        d = e2.y - z2.y; p = fmaf(d, d, p);
        d = e2.z - z2.z; p = fmaf(d, d, p);
        d = e2.w - z2.w; p = fmaf(d, d, p);
        d = e3.x - z3.x; p = fmaf(d, d, p);
        d = e3.y - z3.y; p = fmaf(d, d, p);
        d = e3.z - z3.z; p = fmaf(d, d, p);
        d = e3.w - z3.w; p = fmaf(d, d, p);
        // full distance onto all 4 lanes of the row quad (same math as round 6)
        p += __shfl_xor(p, 1);
        p += __shfl_xor(p, 2);
        // dist >= 0: float bits order-preserving; low 32 = row ->
        // first-occurrence tie-break like jnp.argmin.
        unsigned long long key =
            ((unsigned long long)__float_as_uint(p) << 32) | (unsigned)row;
        #pragma unroll
        for (int off = 32; off >= 4; off >>= 1) {
            unsigned long long o = shfl_down_u64(key, off, 64);
            key = o < key ? o : key;
        }
        if (lane == 0) cand[t][wv] = key;
    }
    __syncthreads();

    // ---- block-level reduce: batch t = tid>>4, slot s = tid&15 ----
    if (tid < 256) {
        const int t = tid >> 4, s = tid & 15;
        unsigned long long k = cand[t][s];
        #pragma unroll
        for (int off = 8; off > 0; off >>= 1) {
            unsigned long long o = shfl_down_u64(k, off, 16);
            k = o < k ? o : k;
        }
        if (s == 0) ws[(bt * 16 + t) * 16 + rt] = k;
    }
}

// ---------------- K2: argmin combine + neighbors + decode ----------------
__global__ __launch_bounds__(128) void k_finish(
    const float* __restrict__ emb,
    const float* __restrict__ w_d,  const float* __restrict__ b_d,
    const float* __restrict__ w_d0, const float* __restrict__ b_d0,
    const float* __restrict__ w_d1, const float* __restrict__ b_d1,
    const float* __restrict__ w_d2, const float* __restrict__ b_d2,
    const unsigned long long* __restrict__ ws,
    float* __restrict__ out)
{
    const int b    = blockIdx.x;
    const int tid  = threadIdx.x;
    const int wv   = tid >> 6;
    const int lane = tid & 63;

    __shared__ float zbuf[2][64];
    __shared__ float t0s[2][100];
    __shared__ float t1s[2][60];
    __shared__ float t2s[2][30];
    __shared__ int nmin_s;

    if (tid < 16) {
        unsigned long long k = ws[b * 16 + tid];
        #pragma unroll
        for (int off = 8; off > 0; off >>= 1) {
            unsigned long long o = shfl_down_u64(k, off, 16);
            k = o < k ? o : k;
        }
        if (tid == 0) nmin_s = (int)(k & 0xffffffffu);
    }
    __syncthreads();
    const int nmin = nmin_s;
    const int nx = nmin >> 6, ny = nmin & 63;

    if (tid < 64) {
        const int j = tid;
        zbuf[0][j] = out[b * 64 + j];                     // z_e (written by K1)
        float zq = emb[nmin * 64 + j];
        zbuf[1][j] = zq;
        out[16384 + b * 64 + j] = zq;                     // z_q
        const int nb = 32768 + b * 320;                   // z_q_neighbors [B,5,64]
        out[nb + j] = zq;                                 // row 0: z_q
        float up = (nx < 63) ? emb[((nx + 1) * 64 + ny) * 64 + j] : 0.f;
        out[nb + 64 + j] = up;                            // row 1: up
        float dn = (nx > 0) ? emb[((nx - 1) * 64 + ny) * 64 + j] : 0.f;
        out[nb + 128 + j] = dn;                           // row 2: down
        out[nb + 192 + j] = 0.f;                          // row 3: right (faithful bug)
        float lf = (ny > 0) ? emb[(nx * 64 + (ny - 1)) * 64 + j] : 0.f;
        out[nb + 256 + j] = lf;                           // row 4: left
    }
    __syncthreads();

    // decode: wave 0 -> z_e, wave 1 -> z_q
    for (int jj = lane; jj < 100; jj += 64) {
        float acc = b_d[jj];
        for (int i = 0; i < 64; ++i)
            acc = fmaf(zbuf[wv][i], w_d[i * 100 + jj], acc);
        t0s[wv][jj] = lrelu(acc);
    }
    __syncthreads();
    if (lane < 60) {
        float acc = b_d0[lane];
        for (int i = 0; i < 100; ++i)
            acc = fmaf(t0s[wv][i], w_d0[i * 60 + lane], acc);
        t1s[wv][lane] = lrelu(acc);
    }
    __syncthreads();
    if (lane < 30) {
        float acc = b_d1[lane];
        for (int i = 0; i < 60; ++i)
            acc = fmaf(t1s[wv][i], w_d1[i * 30 + lane], acc);
        t2s[wv][lane] = lrelu(acc);
    }
    __syncthreads();
    if (lane == 0) {
        float acc = b_d2[0];
        for (int i = 0; i < 30; ++i)
            acc = fmaf(t2s[wv][i], w_d2[i], acc);
        float r = lrelu(acc);
        out[(wv == 0 ? 114688 : 114944) + b] = r;         // decoder_e / decoder_q
    }
}

extern "C" void kernel_launch(void* const* d_in, const int* in_sizes, int n_in,
                              void* d_out, int out_size, void* d_ws, size_t ws_size,
                              hipStream_t stream) {
    (void)in_sizes; (void)n_in; (void)ws_size; (void)out_size;
    const float* x    = (const float*)d_in[0];
    const float* eps  = (const float*)d_in[1];
    const float* emb  = (const float*)d_in[2];
    const float* w_e0 = (const float*)d_in[3];
    const float* b_e0 = (const float*)d_in[4];
    const float* w_e1 = (const float*)d_in[5];
    const float* b_e1 = (const float*)d_in[6];
    const float* w_mu = (const float*)d_in[7];
    const float* b_mu = (const float*)d_in[8];
    const float* w_lv = (const float*)d_in[9];
    const float* b_lv = (const float*)d_in[10];
    const float* w_d  = (const float*)d_in[11];
    const float* b_d  = (const float*)d_in[12];
    const float* w_d0 = (const float*)d_in[13];
    const float* b_d0 = (const float*)d_in[14];
    const float* w_d1 = (const float*)d_in[15];
    const float* b_d1 = (const float*)d_in[16];
    const float* w_d2 = (const float*)d_in[17];
    const float* b_d2 = (const float*)d_in[18];
    float* out = (float*)d_out;
    unsigned long long* ws = (unsigned long long*)d_ws;

    k_scan_enc<<<256, 1024, 0, stream>>>(x, eps, emb, w_e0, b_e0, w_e1, b_e1,
                                         w_mu, b_mu, w_lv, b_lv, out, ws);
    k_finish<<<256, 128, 0, stream>>>(emb, w_d, b_d, w_d0, b_d0,
                                      w_d1, b_d1, w_d2, b_d2, ws, out);
}

// Round 8
// 32.197 us; speedup vs baseline: 1.2480x; 1.1092x over previous
//
#include <hip/hip_runtime.h>

__device__ __forceinline__ float lrelu(float v) { return v >= 0.f ? v : 0.01f * v; }

__device__ __forceinline__ unsigned long long shfl_down_u64(unsigned long long v, int off, int width) {
    unsigned lo = (unsigned)(v & 0xffffffffu);
    unsigned hi = (unsigned)(v >> 32);
    lo = __shfl_down(lo, off, width);
    hi = __shfl_down(hi, off, width);
    return ((unsigned long long)hi << 32) | lo;
}

__device__ __forceinline__ unsigned long long u64min(unsigned long long a, unsigned long long b) {
    return a < b ? a : b;
}

// ---------------- K1: fused encode + table-tiled SOM scan (register-tiled) ----------------
// Grid 256 = 16 batch-tiles (bt) x 16 row-tiles (rt). Block: 256 rows x 16 batches.
// Wave w: row sub-tile (w&3) (64 rows), batches (w>>2)*4 .. +3.
// Lane: row-group g = lane>>2, dim-chunk q = lane&3 (dims q*16..+15), holds
// 4 rows {rt*256+(w&3)*64 + k*16 + g, k=0..3} x 16 dims = 64 VGPRs.
// Per batch t: 4 LDS z-reads + 64 fma + 8 quad-xor shuffles + in-lane min(4 keys)
// + 4-step wave key-reduce -> cand. 20 LDS-pipe ops per 64 rows (vs 14 per 16 rows before).
__global__ __launch_bounds__(1024) void k_scan_enc(
    const float* __restrict__ x, const float* __restrict__ eps,
    const float* __restrict__ emb,
    const float* __restrict__ w_e0, const float* __restrict__ b_e0,
    const float* __restrict__ w_e1, const float* __restrict__ b_e1,
    const float* __restrict__ w_mu, const float* __restrict__ b_mu,
    const float* __restrict__ w_lv, const float* __restrict__ b_lv,
    float* __restrict__ out, unsigned long long* __restrict__ ws)
{
    const int bt   = blockIdx.x >> 4;
    const int rt   = blockIdx.x & 15;
    const int tid  = threadIdx.x;
    const int w    = tid >> 6;
    const int lane = tid & 63;

    __shared__ float h1s[16][52];
    __shared__ __align__(16) float zs[16][64];
    __shared__ unsigned long long cand[16][4];    // [batch-local][row-subtile]

    // ---- encode batch j = bt*16 + w (wave w encodes one batch; bit-identical
    //      across all rt blocks; only rt==0 writes z_e out) ----
    const int j = bt * 16 + w;
    if (lane < 50) {
        const float xv = x[j];
        float acc = b_e1[lane];
        #pragma unroll
        for (int i = 0; i < 10; ++i) {
            float h = lrelu(fmaf(xv, w_e0[i], b_e0[i]));
            acc = fmaf(h, w_e1[i * 50 + lane], acc);
        }
        h1s[w][lane] = lrelu(acc);                // wave-private, no barrier needed
    }
    {
        float mu = b_mu[lane];
        float lv = b_lv[lane];
        for (int i = 0; i < 50; ++i) {
            float h = h1s[w][i];
            mu = fmaf(h, w_mu[i * 64 + lane], mu);
            lv = fmaf(h, w_lv[i * 64 + lane], lv);
        }
        float z = fmaf(eps[j * 64 + lane], expf(0.5f * lv), mu);
        zs[w][lane] = z;
        if (rt == 0) out[j * 64 + lane] = z;      // z_e written exactly once per batch
    }

    // ---- load 4 rows x 16 dims into registers (coalesced: per k the wave
    //      reads a contiguous 4 KB span) ----
    const int g = lane >> 2;
    const int q = lane & 3;
    const int rowBase = rt * 256 + (w & 3) * 64 + g;   // + k*16
    float4 e[16];
    #pragma unroll
    for (int k = 0; k < 4; ++k) {
        const float* rp = emb + (rowBase + k * 16) * 64 + q * 16;
        e[k * 4 + 0] = *reinterpret_cast<const float4*>(rp + 0);
        e[k * 4 + 1] = *reinterpret_cast<const float4*>(rp + 4);
        e[k * 4 + 2] = *reinterpret_cast<const float4*>(rp + 8);
        e[k * 4 + 3] = *reinterpret_cast<const float4*>(rp + 12);
    }
    __syncthreads();                              // zs ready (cross-wave reads below)

    #pragma unroll 1
    for (int t = 0; t < 4; ++t) {
        const int jloc = (w >> 2) * 4 + t;        // batch-local index
        const float* zb = &zs[jloc][q * 16];
        const float4 z0 = *reinterpret_cast<const float4*>(zb + 0);
        const float4 z1 = *reinterpret_cast<const float4*>(zb + 4);
        const float4 z2 = *reinterpret_cast<const float4*>(zb + 8);
        const float4 z3 = *reinterpret_cast<const float4*>(zb + 12);

        unsigned long long best = ~0ull;
        #pragma unroll
        for (int k = 0; k < 4; ++k) {
            float p = 0.f, d;
            d = e[k*4+0].x - z0.x; p = fmaf(d, d, p);
            d = e[k*4+0].y - z0.y; p = fmaf(d, d, p);
            d = e[k*4+0].z - z0.z; p = fmaf(d, d, p);
            d = e[k*4+0].w - z0.w; p = fmaf(d, d, p);
            d = e[k*4+1].x - z1.x; p = fmaf(d, d, p);
            d = e[k*4+1].y - z1.y; p = fmaf(d, d, p);
            d = e[k*4+1].z - z1.z; p = fmaf(d, d, p);
            d = e[k*4+1].w - z1.w; p = fmaf(d, d, p);
            d = e[k*4+2].x - z2.x; p = fmaf(d, d, p);
            d = e[k*4+2].y - z2.y; p = fmaf(d, d, p);
            d = e[k*4+2].z - z2.z; p = fmaf(d, d, p);
            d = e[k*4+2].w - z2.w; p = fmaf(d, d, p);
            d = e[k*4+3].x - z3.x; p = fmaf(d, d, p);
            d = e[k*4+3].y - z3.y; p = fmaf(d, d, p);
            d = e[k*4+3].z - z3.z; p = fmaf(d, d, p);
            d = e[k*4+3].w - z3.w; p = fmaf(d, d, p);
            // full distance across the quad (same tree as the passing kernel)
            p += __shfl_xor(p, 1);
            p += __shfl_xor(p, 2);
            // dist >= 0: float bits order-preserving; low 32 = row ->
            // first-occurrence tie-break like jnp.argmin.
            const unsigned long long key =
                ((unsigned long long)__float_as_uint(p) << 32) |
                (unsigned)(rowBase + k * 16);
            best = u64min(best, key);             // in-lane min over 4 rows
        }
        // wave-level min: quad-lanes hold identical values, so reducing
        // offs 32,16,8,4 covers all 16 row-groups.
        #pragma unroll
        for (int off = 32; off >= 4; off >>= 1)
            best = u64min(best, shfl_down_u64(best, off, 64));
        if (lane == 0) cand[jloc][w & 3] = best;
    }
    __syncthreads();

    // ---- block-level reduce: 16 batches x 4 sub-tiles -> ws[batch][rt] ----
    if (tid < 64) {
        const int t = tid >> 2, s = tid & 3;
        unsigned long long k = cand[t][s];
        k = u64min(k, shfl_down_u64(k, 2, 4));
        k = u64min(k, shfl_down_u64(k, 1, 4));
        if (s == 0) ws[(bt * 16 + t) * 16 + rt] = k;
    }
}

// ---------------- K2: argmin combine + neighbors + decode ----------------
__global__ __launch_bounds__(128) void k_finish(
    const float* __restrict__ emb,
    const float* __restrict__ w_d,  const float* __restrict__ b_d,
    const float* __restrict__ w_d0, const float* __restrict__ b_d0,
    const float* __restrict__ w_d1, const float* __restrict__ b_d1,
    const float* __restrict__ w_d2, const float* __restrict__ b_d2,
    const unsigned long long* __restrict__ ws,
    float* __restrict__ out)
{
    const int b    = blockIdx.x;
    const int tid  = threadIdx.x;
    const int wv   = tid >> 6;
    const int lane = tid & 63;

    __shared__ float zbuf[2][64];
    __shared__ float t0s[2][100];
    __shared__ float t1s[2][60];
    __shared__ float t2s[2][30];
    __shared__ int nmin_s;

    if (tid < 16) {
        unsigned long long k = ws[b * 16 + tid];
        #pragma unroll
        for (int off = 8; off > 0; off >>= 1) {
            unsigned long long o = shfl_down_u64(k, off, 16);
            k = o < k ? o : k;
        }
        if (tid == 0) nmin_s = (int)(k & 0xffffffffu);
    }
    __syncthreads();
    const int nmin = nmin_s;
    const int nx = nmin >> 6, ny = nmin & 63;

    if (tid < 64) {
        const int j = tid;
        zbuf[0][j] = out[b * 64 + j];                     // z_e (written by K1)
        float zq = emb[nmin * 64 + j];
        zbuf[1][j] = zq;
        out[16384 + b * 64 + j] = zq;                     // z_q
        const int nb = 32768 + b * 320;                   // z_q_neighbors [B,5,64]
        out[nb + j] = zq;                                 // row 0: z_q
        float up = (nx < 63) ? emb[((nx + 1) * 64 + ny) * 64 + j] : 0.f;
        out[nb + 64 + j] = up;                            // row 1: up
        float dn = (nx > 0) ? emb[((nx - 1) * 64 + ny) * 64 + j] : 0.f;
        out[nb + 128 + j] = dn;                           // row 2: down
        out[nb + 192 + j] = 0.f;                          // row 3: right (faithful bug)
        float lf = (ny > 0) ? emb[(nx * 64 + (ny - 1)) * 64 + j] : 0.f;
        out[nb + 256 + j] = lf;                           // row 4: left
    }
    __syncthreads();

    // decode: wave 0 -> z_e, wave 1 -> z_q
    for (int jj = lane; jj < 100; jj += 64) {
        float acc = b_d[jj];
        for (int i = 0; i < 64; ++i)
            acc = fmaf(zbuf[wv][i], w_d[i * 100 + jj], acc);
        t0s[wv][jj] = lrelu(acc);
    }
    __syncthreads();
    if (lane < 60) {
        float acc = b_d0[lane];
        for (int i = 0; i < 100; ++i)
            acc = fmaf(t0s[wv][i], w_d0[i * 60 + lane], acc);
        t1s[wv][lane] = lrelu(acc);
    }
    __syncthreads();
    if (lane < 30) {
        float acc = b_d1[lane];
        for (int i = 0; i < 60; ++i)
            acc = fmaf(t1s[wv][i], w_d1[i * 30 + lane], acc);
        t2s[wv][lane] = lrelu(acc);
    }
    __syncthreads();
    if (lane == 0) {
        float acc = b_d2[0];
        for (int i = 0; i < 30; ++i)
            acc = fmaf(t2s[wv][i], w_d2[i], acc);
        float r = lrelu(acc);
        out[(wv == 0 ? 114688 : 114944) + b] = r;         // decoder_e / decoder_q
    }
}

extern "C" void kernel_launch(void* const* d_in, const int* in_sizes, int n_in,
                              void* d_out, int out_size, void* d_ws, size_t ws_size,
                              hipStream_t stream) {
    (void)in_sizes; (void)n_in; (void)ws_size; (void)out_size;
    const float* x    = (const float*)d_in[0];
    const float* eps  = (const float*)d_in[1];
    const float* emb  = (const float*)d_in[2];
    const float* w_e0 = (const float*)d_in[3];
    const float* b_e0 = (const float*)d_in[4];
    const float* w_e1 = (const float*)d_in[5];
    const float* b_e1 = (const float*)d_in[6];
    const float* w_mu = (const float*)d_in[7];
    const float* b_mu = (const float*)d_in[8];
    const float* w_lv = (const float*)d_in[9];
    const float* b_lv = (const float*)d_in[10];
    const float* w_d  = (const float*)d_in[11];
    const float* b_d  = (const float*)d_in[12];
    const float* w_d0 = (const float*)d_in[13];
    const float* b_d0 = (const float*)d_in[14];
    const float* w_d1 = (const float*)d_in[15];
    const float* b_d1 = (const float*)d_in[16];
    const float* w_d2 = (const float*)d_in[17];
    const float* b_d2 = (const float*)d_in[18];
    float* out = (float*)d_out;
    unsigned long long* ws = (unsigned long long*)d_ws;

    k_scan_enc<<<256, 1024, 0, stream>>>(x, eps, emb, w_e0, b_e0, w_e1, b_e1,
                                         w_mu, b_mu, w_lv, b_lv, out, ws);
    k_finish<<<256, 128, 0, stream>>>(emb, w_d, b_d, w_d0, b_d0,
                                      w_d1, b_d1, w_d2, b_d2, ws, out);
}

// Round 9
// 31.154 us; speedup vs baseline: 1.2898x; 1.0335x over previous
//
#include <hip/hip_runtime.h>

__device__ __forceinline__ float lrelu(float v) { return v >= 0.f ? v : 0.01f * v; }

__device__ __forceinline__ unsigned long long shfl_down_u64(unsigned long long v, int off, int width) {
    unsigned lo = (unsigned)(v & 0xffffffffu);
    unsigned hi = (unsigned)(v >> 32);
    lo = __shfl_down(lo, off, width);
    hi = __shfl_down(hi, off, width);
    return ((unsigned long long)hi << 32) | lo;
}
__device__ __forceinline__ unsigned long long u64min(unsigned long long a, unsigned long long b) {
    return a < b ? a : b;
}

// Single fused kernel. Grid 256 = 64 batch-tiles (bt, 4 batches) x 4 row-tiles
// (rt, 1024 rows). Scan layout per wave = round 8's validated one: 64 rows x
// 4 batches, 4 rows x 16 dims in regs per lane (quad dim-split), xor1/xor2
// quad reduce -> u64 key (distbits<<32 | row) -> exact jnp.argmin tie-break.
// Finish (z_e/z_q/neighbors/decodes) by the last-arriving block per bt:
// candidates via device-scope atomicExch into unique ws slots (stateless,
// rewritten every call), __threadfence + atomicAdd counter; (old&3)==3 ->
// finisher (mod trick: exactly one finisher regardless of counter base).
__global__ __launch_bounds__(1024) void vae_mega(
    const float* __restrict__ x, const float* __restrict__ eps,
    const float* __restrict__ emb,
    const float* __restrict__ w_e0, const float* __restrict__ b_e0,
    const float* __restrict__ w_e1, const float* __restrict__ b_e1,
    const float* __restrict__ w_mu, const float* __restrict__ b_mu,
    const float* __restrict__ w_lv, const float* __restrict__ b_lv,
    const float* __restrict__ w_d,  const float* __restrict__ b_d,
    const float* __restrict__ w_d0, const float* __restrict__ b_d0,
    const float* __restrict__ w_d1, const float* __restrict__ b_d1,
    const float* __restrict__ w_d2, const float* __restrict__ b_d2,
    float* __restrict__ out,
    unsigned long long* __restrict__ wsK,   // [64 bt][4 rt] 64B lines, 4 u64 used
    unsigned int* __restrict__ wsC)         // [64 bt] counters, 64B stride
{
    const int bt   = blockIdx.x >> 2;
    const int rt   = blockIdx.x & 3;
    const int tid  = threadIdx.x;
    const int w    = tid >> 6;
    const int lane = tid & 63;

    __shared__ float h1s[4][52];
    __shared__ __align__(16) float zs[4][64];     // z_e for the 4 batches
    __shared__ __align__(16) float zq_s[4][64];   // z_q (finisher only)
    __shared__ unsigned long long cand[4][16];    // [batch-local][wave]
    __shared__ int nmin_s[4];
    __shared__ int fin_s;
    __shared__ float t0s[4][2][100];
    __shared__ float t1s[4][2][60];
    __shared__ float t2s[4][2][30];

    // ---- table fragment: issue global loads first (latency hidden by encode)
    const int g = lane >> 2;
    const int q = lane & 3;
    const int rowBase = rt * 1024 + w * 64 + g;   // rows rowBase + k*16
    float4 e[16];
    #pragma unroll
    for (int k = 0; k < 4; ++k) {
        const float* rp = emb + (rowBase + k * 16) * 64 + q * 16;
        e[k * 4 + 0] = *reinterpret_cast<const float4*>(rp + 0);
        e[k * 4 + 1] = *reinterpret_cast<const float4*>(rp + 4);
        e[k * 4 + 2] = *reinterpret_cast<const float4*>(rp + 8);
        e[k * 4 + 3] = *reinterpret_cast<const float4*>(rp + 12);
    }

    // ---- encode: wave w<4 encodes batch bt*4+w (wave-private LDS pattern,
    //      validated in rounds 7/8) ----
    if (w < 4) {
        const int j = bt * 4 + w;
        if (lane < 50) {
            const float xv = x[j];
            float acc = b_e1[lane];
            #pragma unroll
            for (int i = 0; i < 10; ++i) {
                float h = lrelu(fmaf(xv, w_e0[i], b_e0[i]));
                acc = fmaf(h, w_e1[i * 50 + lane], acc);
            }
            h1s[w][lane] = lrelu(acc);
        }
        float mu = b_mu[lane];
        float lv = b_lv[lane];
        for (int i = 0; i < 50; ++i) {
            float h = h1s[w][i];
            mu = fmaf(h, w_mu[i * 64 + lane], mu);
            lv = fmaf(h, w_lv[i * 64 + lane], lv);
        }
        zs[w][lane] = fmaf(eps[j * 64 + lane], expf(0.5f * lv), mu);
    }
    __syncthreads();

    // ---- scan: 4 batches per wave, same math/order as round 8 ----
    #pragma unroll 1
    for (int t = 0; t < 4; ++t) {
        const float* zb = &zs[t][q * 16];
        const float4 z0 = *reinterpret_cast<const float4*>(zb + 0);
        const float4 z1 = *reinterpret_cast<const float4*>(zb + 4);
        const float4 z2 = *reinterpret_cast<const float4*>(zb + 8);
        const float4 z3 = *reinterpret_cast<const float4*>(zb + 12);

        unsigned long long best = ~0ull;
        #pragma unroll
        for (int k = 0; k < 4; ++k) {
            float p = 0.f, d;
            d = e[k*4+0].x - z0.x; p = fmaf(d, d, p);
            d = e[k*4+0].y - z0.y; p = fmaf(d, d, p);
            d = e[k*4+0].z - z0.z; p = fmaf(d, d, p);
            d = e[k*4+0].w - z0.w; p = fmaf(d, d, p);
            d = e[k*4+1].x - z1.x; p = fmaf(d, d, p);
            d = e[k*4+1].y - z1.y; p = fmaf(d, d, p);
            d = e[k*4+1].z - z1.z; p = fmaf(d, d, p);
            d = e[k*4+1].w - z1.w; p = fmaf(d, d, p);
            d = e[k*4+2].x - z2.x; p = fmaf(d, d, p);
            d = e[k*4+2].y - z2.y; p = fmaf(d, d, p);
            d = e[k*4+2].z - z2.z; p = fmaf(d, d, p);
            d = e[k*4+2].w - z2.w; p = fmaf(d, d, p);
            d = e[k*4+3].x - z3.x; p = fmaf(d, d, p);
            d = e[k*4+3].y - z3.y; p = fmaf(d, d, p);
            d = e[k*4+3].z - z3.z; p = fmaf(d, d, p);
            d = e[k*4+3].w - z3.w; p = fmaf(d, d, p);
            p += __shfl_xor(p, 1);
            p += __shfl_xor(p, 2);
            const unsigned long long key =
                ((unsigned long long)__float_as_uint(p) << 32) |
                (unsigned)(rowBase + k * 16);
            best = u64min(best, key);
        }
        #pragma unroll
        for (int off = 32; off >= 4; off >>= 1)
            best = u64min(best, shfl_down_u64(best, off, 64));
        if (lane == 0) cand[t][w] = best;
    }
    __syncthreads();

    // ---- block reduce -> ws slots -> counter (single wave: stores ordered
    //      before tid0's fence via the wave's vmcnt wait) ----
    if (tid < 64) {
        const int t = tid >> 4, s = tid & 15;
        unsigned long long k = cand[t][s];
        #pragma unroll
        for (int off = 8; off > 0; off >>= 1)
            k = u64min(k, shfl_down_u64(k, off, 16));
        if (s == 0)
            atomicExch(&wsK[(bt * 4 + rt) * 8 + t], k);   // device-scope write
        if (tid == 0) {
            __threadfence();
            const unsigned old = atomicAdd(&wsC[bt * 16], 1u);
            fin_s = ((old & 3u) == 3u);
        }
    }
    __syncthreads();
    if (!fin_s) return;

    // ================= finisher: 4 batches of this bt =================
    if (tid < 16) {                     // lane = rtIdx*4 + t
        unsigned long long k =
            atomicOr(&wsK[(bt * 4 + (tid >> 2)) * 8 + (tid & 3)], 0ull);
        k = u64min(k, shfl_down_u64(k, 8, 16));
        k = u64min(k, shfl_down_u64(k, 4, 16));
        if (tid < 4) nmin_s[tid] = (int)(k & 0xffffffffu);
    }
    __syncthreads();

    // phase A: waves 8..11 -> batch i: z_e out, z_q, neighbors
    if (w >= 8 && w < 12) {
        const int i = w - 8;
        const int b = bt * 4 + i;
        const int nmin = nmin_s[i];
        const int nx = nmin >> 6, ny = nmin & 63;
        const int j = lane;
        out[b * 64 + j] = zs[i][j];                       // z_e
        const float zq = emb[nmin * 64 + j];
        zq_s[i][j] = zq;
        out[16384 + b * 64 + j] = zq;                     // z_q
        const int nb = 32768 + b * 320;                   // z_q_neighbors [B,5,64]
        out[nb + j] = zq;                                 // row 0: z_q
        float up = (nx < 63) ? emb[((nx + 1) * 64 + ny) * 64 + j] : 0.f;
        out[nb + 64 + j] = up;                            // row 1: up
        float dn = (nx > 0) ? emb[((nx - 1) * 64 + ny) * 64 + j] : 0.f;
        out[nb + 128 + j] = dn;                           // row 2: down
        out[nb + 192 + j] = 0.f;                          // row 3: right (faithful bug)
        float lf = (ny > 0) ? emb[(nx * 64 + (ny - 1)) * 64 + j] : 0.f;
        out[nb + 256 + j] = lf;                           // row 4: left
    }
    __syncthreads();

    // decode: waves 0..7 -> batch i = w>>1, input sel = w&1 (0=z_e, 1=z_q)
    const int di  = w >> 1;
    const int sel = w & 1;
    const bool dec = (w < 8);
    const float* zv = sel ? zq_s[di] : zs[di];

    if (dec) {
        for (int jj = lane; jj < 100; jj += 64) {
            float acc = b_d[jj];
            for (int i = 0; i < 64; ++i)
                acc = fmaf(zv[i], w_d[i * 100 + jj], acc);
            t0s[di][sel][jj] = lrelu(acc);
        }
    }
    __syncthreads();
    if (dec && lane < 60) {
        float acc = b_d0[lane];
        for (int i = 0; i < 100; ++i)
            acc = fmaf(t0s[di][sel][i], w_d0[i * 60 + lane], acc);
        t1s[di][sel][lane] = lrelu(acc);
    }
    __syncthreads();
    if (dec && lane < 30) {
        float acc = b_d1[lane];
        for (int i = 0; i < 60; ++i)
            acc = fmaf(t1s[di][sel][i], w_d1[i * 30 + lane], acc);
        t2s[di][sel][lane] = lrelu(acc);
    }
    __syncthreads();
    if (dec && lane == 0) {
        float acc = b_d2[0];
        for (int i = 0; i < 30; ++i)
            acc = fmaf(t2s[di][sel][i], w_d2[i], acc);
        const float r = lrelu(acc);
        out[(sel ? 114944 : 114688) + bt * 4 + di] = r;   // decoder_q / decoder_e
    }
}

extern "C" void kernel_launch(void* const* d_in, const int* in_sizes, int n_in,
                              void* d_out, int out_size, void* d_ws, size_t ws_size,
                              hipStream_t stream) {
    (void)in_sizes; (void)n_in; (void)ws_size; (void)out_size;
    const float* x    = (const float*)d_in[0];
    const float* eps  = (const float*)d_in[1];
    const float* emb  = (const float*)d_in[2];
    const float* w_e0 = (const float*)d_in[3];
    const float* b_e0 = (const float*)d_in[4];
    const float* w_e1 = (const float*)d_in[5];
    const float* b_e1 = (const float*)d_in[6];
    const float* w_mu = (const float*)d_in[7];
    const float* b_mu = (const float*)d_in[8];
    const float* w_lv = (const float*)d_in[9];
    const float* b_lv = (const float*)d_in[10];
    const float* w_d  = (const float*)d_in[11];
    const float* b_d  = (const float*)d_in[12];
    const float* w_d0 = (const float*)d_in[13];
    const float* b_d0 = (const float*)d_in[14];
    const float* w_d1 = (const float*)d_in[15];
    const float* b_d1 = (const float*)d_in[16];
    const float* w_d2 = (const float*)d_in[17];
    const float* b_d2 = (const float*)d_in[18];
    float* out = (float*)d_out;
    unsigned long long* wsK = (unsigned long long*)d_ws;            // 64*4*64B = 16 KB
    unsigned int* wsC = (unsigned int*)((char*)d_ws + 65536);       // 64 counters, 64B stride

    vae_mega<<<256, 1024, 0, stream>>>(
        x, eps, emb, w_e0, b_e0, w_e1, b_e1, w_mu, b_mu, w_lv, b_lv,
        w_d, b_d, w_d0, b_d0, w_d1, b_d1, w_d2, b_d2, out, wsK, wsC);
}

// Round 10
// 25.362 us; speedup vs baseline: 1.5843x; 1.2284x over previous
//
#include <hip/hip_runtime.h>

__device__ __forceinline__ float lrelu(float v) { return v >= 0.f ? v : 0.01f * v; }

__device__ __forceinline__ unsigned long long shfl_down_u64(unsigned long long v, int off, int width) {
    unsigned lo = (unsigned)(v & 0xffffffffu);
    unsigned hi = (unsigned)(v >> 32);
    lo = __shfl_down(lo, off, width);
    hi = __shfl_down(hi, off, width);
    return ((unsigned long long)hi << 32) | lo;
}
__device__ __forceinline__ unsigned long long u64min(unsigned long long a, unsigned long long b) {
    return a < b ? a : b;
}

// Single fused kernel (structure = round 9, which passed absmax 0.0) with ALL
// MLP weights staged to LDS so the serial fma loops read ds_read (~60cy,
// pipelined) instead of per-iteration exposed L2 latency (~200cy).
// Math order everywhere is bit-identical to round 9 -> same argmin, same out.
__global__ __launch_bounds__(1024) void vae_mega(
    const float* __restrict__ x, const float* __restrict__ eps,
    const float* __restrict__ emb,
    const float* __restrict__ w_e0, const float* __restrict__ b_e0,
    const float* __restrict__ w_e1, const float* __restrict__ b_e1,
    const float* __restrict__ w_mu, const float* __restrict__ b_mu,
    const float* __restrict__ w_lv, const float* __restrict__ b_lv,
    const float* __restrict__ w_d,  const float* __restrict__ b_d,
    const float* __restrict__ w_d0, const float* __restrict__ b_d0,
    const float* __restrict__ w_d1, const float* __restrict__ b_d1,
    const float* __restrict__ w_d2, const float* __restrict__ b_d2,
    float* __restrict__ out,
    unsigned long long* __restrict__ wsK,   // [64 bt][4 rt] 64B lines, 4 u64 used
    unsigned int* __restrict__ wsC)         // [64 bt] counters, 64B stride
{
    const int bt   = blockIdx.x >> 2;
    const int rt   = blockIdx.x & 3;
    const int tid  = threadIdx.x;
    const int w    = tid >> 6;
    const int lane = tid & 63;

    // encoder weights (staged by every block)
    __shared__ __align__(16) float L_wmu[3200], L_wlv[3200], L_we1[500];
    __shared__ float L_we0[10], L_be0[10], L_be1[50], L_bmu[64], L_blv[64];
    // decoder weights (staged by finisher only)
    __shared__ __align__(16) float L_wd[6400], L_wd0[6000], L_wd1[1800];
    __shared__ float L_bd[100], L_bd0[60], L_bd1[30], L_wd2[30];

    __shared__ float h1s[4][52];
    __shared__ __align__(16) float zs[4][64];
    __shared__ __align__(16) float zq_s[4][64];
    __shared__ unsigned long long cand[4][16];
    __shared__ int nmin_s[4];
    __shared__ int fin_s;
    __shared__ float t0s[4][2][100];
    __shared__ float t1s[4][2][60];
    __shared__ float t2s[4][2][30];

    // ---- table fragment: issue global loads first (latency hidden by staging)
    const int g = lane >> 2;
    const int q = lane & 3;
    const int rowBase = rt * 1024 + w * 64 + g;   // rows rowBase + k*16
    float4 e[16];
    #pragma unroll
    for (int k = 0; k < 4; ++k) {
        const float* rp = emb + (rowBase + k * 16) * 64 + q * 16;
        e[k * 4 + 0] = *reinterpret_cast<const float4*>(rp + 0);
        e[k * 4 + 1] = *reinterpret_cast<const float4*>(rp + 4);
        e[k * 4 + 2] = *reinterpret_cast<const float4*>(rp + 8);
        e[k * 4 + 3] = *reinterpret_cast<const float4*>(rp + 12);
    }

    // ---- stage encoder weights (cooperative, vectorized, pipelined) ----
    {
        const float4* s4; float4* d4;
        s4 = (const float4*)w_mu; d4 = (float4*)L_wmu;
        for (int i = tid; i < 800; i += 1024) d4[i] = s4[i];
        s4 = (const float4*)w_lv; d4 = (float4*)L_wlv;
        for (int i = tid; i < 800; i += 1024) d4[i] = s4[i];
        s4 = (const float4*)w_e1; d4 = (float4*)L_we1;
        for (int i = tid; i < 125; i += 1024) d4[i] = s4[i];
        if (tid < 10) { L_we0[tid] = w_e0[tid]; L_be0[tid] = b_e0[tid]; }
        if (tid < 50) L_be1[tid] = b_e1[tid];
        if (tid < 64) { L_bmu[tid] = b_mu[tid]; L_blv[tid] = b_lv[tid]; }
    }
    __syncthreads();

    // ---- encode: wave w<4 encodes batch bt*4+w (same op order as round 9) ----
    if (w < 4) {
        const int j = bt * 4 + w;
        if (lane < 50) {
            const float xv = x[j];
            float acc = L_be1[lane];
            #pragma unroll
            for (int i = 0; i < 10; ++i) {
                float h = lrelu(fmaf(xv, L_we0[i], L_be0[i]));
                acc = fmaf(h, L_we1[i * 50 + lane], acc);
            }
            h1s[w][lane] = lrelu(acc);
        }
        float mu = L_bmu[lane];
        float lv = L_blv[lane];
        for (int i = 0; i < 50; ++i) {
            float h = h1s[w][i];
            mu = fmaf(h, L_wmu[i * 64 + lane], mu);
            lv = fmaf(h, L_wlv[i * 64 + lane], lv);
        }
        zs[w][lane] = fmaf(eps[j * 64 + lane], expf(0.5f * lv), mu);
    }
    __syncthreads();

    // ---- scan: verbatim round 9 (validated, absmax 0.0) ----
    #pragma unroll 1
    for (int t = 0; t < 4; ++t) {
        const float* zb = &zs[t][q * 16];
        const float4 z0 = *reinterpret_cast<const float4*>(zb + 0);
        const float4 z1 = *reinterpret_cast<const float4*>(zb + 4);
        const float4 z2 = *reinterpret_cast<const float4*>(zb + 8);
        const float4 z3 = *reinterpret_cast<const float4*>(zb + 12);

        unsigned long long best = ~0ull;
        #pragma unroll
        for (int k = 0; k < 4; ++k) {
            float p = 0.f, d;
            d = e[k*4+0].x - z0.x; p = fmaf(d, d, p);
            d = e[k*4+0].y - z0.y; p = fmaf(d, d, p);
            d = e[k*4+0].z - z0.z; p = fmaf(d, d, p);
            d = e[k*4+0].w - z0.w; p = fmaf(d, d, p);
            d = e[k*4+1].x - z1.x; p = fmaf(d, d, p);
            d = e[k*4+1].y - z1.y; p = fmaf(d, d, p);
            d = e[k*4+1].z - z1.z; p = fmaf(d, d, p);
            d = e[k*4+1].w - z1.w; p = fmaf(d, d, p);
            d = e[k*4+2].x - z2.x; p = fmaf(d, d, p);
            d = e[k*4+2].y - z2.y; p = fmaf(d, d, p);
            d = e[k*4+2].z - z2.z; p = fmaf(d, d, p);
            d = e[k*4+2].w - z2.w; p = fmaf(d, d, p);
            d = e[k*4+3].x - z3.x; p = fmaf(d, d, p);
            d = e[k*4+3].y - z3.y; p = fmaf(d, d, p);
            d = e[k*4+3].z - z3.z; p = fmaf(d, d, p);
            d = e[k*4+3].w - z3.w; p = fmaf(d, d, p);
            p += __shfl_xor(p, 1);
            p += __shfl_xor(p, 2);
            const unsigned long long key =
                ((unsigned long long)__float_as_uint(p) << 32) |
                (unsigned)(rowBase + k * 16);
            best = u64min(best, key);
        }
        #pragma unroll
        for (int off = 32; off >= 4; off >>= 1)
            best = u64min(best, shfl_down_u64(best, off, 64));
        if (lane == 0) cand[t][w] = best;
    }
    __syncthreads();

    // ---- block reduce -> ws slots -> counter ----
    if (tid < 64) {
        const int t = tid >> 4, s = tid & 15;
        unsigned long long k = cand[t][s];
        #pragma unroll
        for (int off = 8; off > 0; off >>= 1)
            k = u64min(k, shfl_down_u64(k, off, 16));
        if (s == 0)
            atomicExch(&wsK[(bt * 4 + rt) * 8 + t], k);
        if (tid == 0) {
            __threadfence();
            const unsigned old = atomicAdd(&wsC[bt * 16], 1u);
            fin_s = ((old & 3u) == 3u);
        }
    }
    __syncthreads();
    if (!fin_s) return;

    // ================= finisher: 4 batches of this bt =================
    if (tid < 16) {                     // lane = rtIdx*4 + t
        unsigned long long k =
            atomicOr(&wsK[(bt * 4 + (tid >> 2)) * 8 + (tid & 3)], 0ull);
        k = u64min(k, shfl_down_u64(k, 8, 16));
        k = u64min(k, shfl_down_u64(k, 4, 16));
        if (tid < 4) nmin_s[tid] = (int)(k & 0xffffffffu);
    }
    // stage decoder weights (independent of nmin; all threads)
    {
        const float4* s4; float4* d4;
        s4 = (const float4*)w_d;  d4 = (float4*)L_wd;
        for (int i = tid; i < 1600; i += 1024) d4[i] = s4[i];
        s4 = (const float4*)w_d0; d4 = (float4*)L_wd0;
        for (int i = tid; i < 1500; i += 1024) d4[i] = s4[i];
        s4 = (const float4*)w_d1; d4 = (float4*)L_wd1;
        for (int i = tid; i < 450; i += 1024) d4[i] = s4[i];
        if (tid < 100) L_bd[tid]  = b_d[tid];
        if (tid < 60)  L_bd0[tid] = b_d0[tid];
        if (tid < 30)  { L_bd1[tid] = b_d1[tid]; L_wd2[tid] = w_d2[tid]; }
    }
    __syncthreads();

    // phase A: waves 8..11 -> batch i: z_e out, z_q, neighbors
    if (w >= 8 && w < 12) {
        const int i = w - 8;
        const int b = bt * 4 + i;
        const int nmin = nmin_s[i];
        const int nx = nmin >> 6, ny = nmin & 63;
        const int j = lane;
        out[b * 64 + j] = zs[i][j];                       // z_e
        const float zq = emb[nmin * 64 + j];
        zq_s[i][j] = zq;
        out[16384 + b * 64 + j] = zq;                     // z_q
        const int nb = 32768 + b * 320;                   // z_q_neighbors [B,5,64]
        out[nb + j] = zq;                                 // row 0: z_q
        float up = (nx < 63) ? emb[((nx + 1) * 64 + ny) * 64 + j] : 0.f;
        out[nb + 64 + j] = up;                            // row 1: up
        float dn = (nx > 0) ? emb[((nx - 1) * 64 + ny) * 64 + j] : 0.f;
        out[nb + 128 + j] = dn;                           // row 2: down
        out[nb + 192 + j] = 0.f;                          // row 3: right (faithful bug)
        float lf = (ny > 0) ? emb[(nx * 64 + (ny - 1)) * 64 + j] : 0.f;
        out[nb + 256 + j] = lf;                           // row 4: left
    }
    __syncthreads();

    // decode: waves 0..7 -> batch i = w>>1, input sel = w&1 (0=z_e, 1=z_q)
    const int di  = w >> 1;
    const int sel = w & 1;
    const bool dec = (w < 8);
    const float* zv = sel ? zq_s[di] : zs[di];

    if (dec) {
        for (int jj = lane; jj < 100; jj += 64) {
            float acc = L_bd[jj];
            for (int i = 0; i < 64; ++i)
                acc = fmaf(zv[i], L_wd[i * 100 + jj], acc);
            t0s[di][sel][jj] = lrelu(acc);
        }
    }
    __syncthreads();
    if (dec && lane < 60) {
        float acc = L_bd0[lane];
        for (int i = 0; i < 100; ++i)
            acc = fmaf(t0s[di][sel][i], L_wd0[i * 60 + lane], acc);
        t1s[di][sel][lane] = lrelu(acc);
    }
    __syncthreads();
    if (dec && lane < 30) {
        float acc = L_bd1[lane];
        for (int i = 0; i < 60; ++i)
            acc = fmaf(t1s[di][sel][i], L_wd1[i * 30 + lane], acc);
        t2s[di][sel][lane] = lrelu(acc);
    }
    __syncthreads();
    if (dec && lane == 0) {
        float acc = b_d2[0];
        for (int i = 0; i < 30; ++i)
            acc = fmaf(t2s[di][sel][i], L_wd2[i], acc);
        const float r = lrelu(acc);
        out[(sel ? 114944 : 114688) + bt * 4 + di] = r;   // decoder_q / decoder_e
    }
}

extern "C" void kernel_launch(void* const* d_in, const int* in_sizes, int n_in,
                              void* d_out, int out_size, void* d_ws, size_t ws_size,
                              hipStream_t stream) {
    (void)in_sizes; (void)n_in; (void)ws_size; (void)out_size;
    const float* x    = (const float*)d_in[0];
    const float* eps  = (const float*)d_in[1];
    const float* emb  = (const float*)d_in[2];
    const float* w_e0 = (const float*)d_in[3];
    const float* b_e0 = (const float*)d_in[4];
    const float* w_e1 = (const float*)d_in[5];
    const float* b_e1 = (const float*)d_in[6];
    const float* w_mu = (const float*)d_in[7];
    const float* b_mu = (const float*)d_in[8];
    const float* w_lv = (const float*)d_in[9];
    const float* b_lv = (const float*)d_in[10];
    const float* w_d  = (const float*)d_in[11];
    const float* b_d  = (const float*)d_in[12];
    const float* w_d0 = (const float*)d_in[13];
    const float* b_d0 = (const float*)d_in[14];
    const float* w_d1 = (const float*)d_in[15];
    const float* b_d1 = (const float*)d_in[16];
    const float* w_d2 = (const float*)d_in[17];
    const float* b_d2 = (const float*)d_in[18];
    float* out = (float*)d_out;
    unsigned long long* wsK = (unsigned long long*)d_ws;            // 16 KB
    unsigned int* wsC = (unsigned int*)((char*)d_ws + 65536);       // 64 counters, 64B stride

    vae_mega<<<256, 1024, 0, stream>>>(
        x, eps, emb, w_e0, b_e0, w_e1, b_e1, w_mu, b_mu, w_lv, b_lv,
        w_d, b_d, w_d0, b_d0, w_d1, b_d1, w_d2, b_d2, out, wsK, wsC);
}

// Round 11
// 23.277 us; speedup vs baseline: 1.7262x; 1.0896x over previous
//
#include <hip/hip_runtime.h>

__device__ __forceinline__ float lrelu(float v) { return v >= 0.f ? v : 0.01f * v; }

__device__ __forceinline__ unsigned long long shfl_down_u64(unsigned long long v, int off, int width) {
    unsigned lo = (unsigned)(v & 0xffffffffu);
    unsigned hi = (unsigned)(v >> 32);
    lo = __shfl_down(lo, off, width);
    hi = __shfl_down(hi, off, width);
    return ((unsigned long long)hi << 32) | lo;
}
__device__ __forceinline__ unsigned long long u64min(unsigned long long a, unsigned long long b) {
    return a < b ? a : b;
}

__device__ __forceinline__ float dist16(float4 r0, float4 r1, float4 r2, float4 r3,
                                        float4 z0, float4 z1, float4 z2, float4 z3) {
    float p = 0.f, d;
    d = r0.x - z0.x; p = fmaf(d, d, p);
    d = r0.y - z0.y; p = fmaf(d, d, p);
    d = r0.z - z0.z; p = fmaf(d, d, p);
    d = r0.w - z0.w; p = fmaf(d, d, p);
    d = r1.x - z1.x; p = fmaf(d, d, p);
    d = r1.y - z1.y; p = fmaf(d, d, p);
    d = r1.z - z1.z; p = fmaf(d, d, p);
    d = r1.w - z1.w; p = fmaf(d, d, p);
    d = r2.x - z2.x; p = fmaf(d, d, p);
    d = r2.y - z2.y; p = fmaf(d, d, p);
    d = r2.z - z2.z; p = fmaf(d, d, p);
    d = r2.w - z2.w; p = fmaf(d, d, p);
    d = r3.x - z3.x; p = fmaf(d, d, p);
    d = r3.y - z3.y; p = fmaf(d, d, p);
    d = r3.z - z3.z; p = fmaf(d, d, p);
    d = r3.w - z3.w; p = fmaf(d, d, p);
    return p;
}

// Single fused kernel (structure = round 10, passed absmax 0.0). Scan rewritten
// k-outer with minimal live set so row loads are issued ONCE (round 9/10's
// VGPR=52 proved the compiler rematerialized the e[16] tile per t-iteration).
// Key set and per-key fmaf chains bit-identical -> same argmin -> same output.
__global__ __launch_bounds__(1024) void vae_mega(
    const float* __restrict__ x, const float* __restrict__ eps,
    const float* __restrict__ emb,
    const float* __restrict__ w_e0, const float* __restrict__ b_e0,
    const float* __restrict__ w_e1, const float* __restrict__ b_e1,
    const float* __restrict__ w_mu, const float* __restrict__ b_mu,
    const float* __restrict__ w_lv, const float* __restrict__ b_lv,
    const float* __restrict__ w_d,  const float* __restrict__ b_d,
    const float* __restrict__ w_d0, const float* __restrict__ b_d0,
    const float* __restrict__ w_d1, const float* __restrict__ b_d1,
    const float* __restrict__ w_d2, const float* __restrict__ b_d2,
    float* __restrict__ out,
    unsigned long long* __restrict__ wsK,   // [64 bt][4 rt] 64B lines, 4 u64 used
    unsigned int* __restrict__ wsC)         // [64 bt] counters, 64B stride
{
    const int bt   = blockIdx.x >> 2;
    const int rt   = blockIdx.x & 3;
    const int tid  = threadIdx.x;
    const int w    = tid >> 6;
    const int lane = tid & 63;

    // encoder weights (staged by every block)
    __shared__ __align__(16) float L_wmu[3200], L_wlv[3200], L_we1[500];
    __shared__ float L_we0[10], L_be0[10], L_be1[50], L_bmu[64], L_blv[64];
    // decoder weights (staged by finisher only)
    __shared__ __align__(16) float L_wd[6400], L_wd0[6000], L_wd1[1800];
    __shared__ float L_bd[100], L_bd0[60], L_bd1[30], L_wd2[30];

    __shared__ float h1s[4][52];
    __shared__ __align__(16) float zs[4][64];
    __shared__ __align__(16) float zq_s[4][64];
    __shared__ unsigned long long cand[4][16];
    __shared__ int nmin_s[4];
    __shared__ int fin_s;
    __shared__ float t0s[4][2][100];
    __shared__ float t1s[4][2][60];
    __shared__ float t2s[4][2][30];

    // ---- stage encoder weights (cooperative, vectorized, pipelined) ----
    {
        const float4* s4; float4* d4;
        s4 = (const float4*)w_mu; d4 = (float4*)L_wmu;
        for (int i = tid; i < 800; i += 1024) d4[i] = s4[i];
        s4 = (const float4*)w_lv; d4 = (float4*)L_wlv;
        for (int i = tid; i < 800; i += 1024) d4[i] = s4[i];
        s4 = (const float4*)w_e1; d4 = (float4*)L_we1;
        for (int i = tid; i < 125; i += 1024) d4[i] = s4[i];
        if (tid < 10) { L_we0[tid] = w_e0[tid]; L_be0[tid] = b_e0[tid]; }
        if (tid < 50) L_be1[tid] = b_e1[tid];
        if (tid < 64) { L_bmu[tid] = b_mu[tid]; L_blv[tid] = b_lv[tid]; }
    }
    __syncthreads();

    // ---- encode: wave w<4 encodes batch bt*4+w ----
    if (w < 4) {
        const int j = bt * 4 + w;
        if (lane < 50) {
            const float xv = x[j];
            float acc = L_be1[lane];
            #pragma unroll
            for (int i = 0; i < 10; ++i) {
                float h = lrelu(fmaf(xv, L_we0[i], L_be0[i]));
                acc = fmaf(h, L_we1[i * 50 + lane], acc);
            }
            h1s[w][lane] = lrelu(acc);
        }
        float mu = L_bmu[lane];
        float lv = L_blv[lane];
        for (int i = 0; i < 50; ++i) {
            float h = h1s[w][i];
            mu = fmaf(h, L_wmu[i * 64 + lane], mu);
            lv = fmaf(h, L_wlv[i * 64 + lane], lv);
        }
        zs[w][lane] = fmaf(eps[j * 64 + lane], expf(0.5f * lv), mu);
    }
    __syncthreads();

    // ---- scan: k-outer, 4 row-regs live, bestT[] running min (keys identical
    //      to round 10; min over same set -> same argmin) ----
    const int g = lane >> 2;
    const int q = lane & 3;
    const int rowBase = rt * 1024 + w * 64 + g;   // rows rowBase + k*16

    float4 zr[4][4];
    #pragma unroll
    for (int t = 0; t < 4; ++t) {
        const float* zb = &zs[t][q * 16];
        zr[t][0] = *reinterpret_cast<const float4*>(zb + 0);
        zr[t][1] = *reinterpret_cast<const float4*>(zb + 4);
        zr[t][2] = *reinterpret_cast<const float4*>(zb + 8);
        zr[t][3] = *reinterpret_cast<const float4*>(zb + 12);
    }
    unsigned long long bestT[4] = {~0ull, ~0ull, ~0ull, ~0ull};
    #pragma unroll
    for (int k = 0; k < 4; ++k) {
        const float* rp = emb + (rowBase + k * 16) * 64 + q * 16;
        const float4 r0 = *reinterpret_cast<const float4*>(rp + 0);
        const float4 r1 = *reinterpret_cast<const float4*>(rp + 4);
        const float4 r2 = *reinterpret_cast<const float4*>(rp + 8);
        const float4 r3 = *reinterpret_cast<const float4*>(rp + 12);
        #pragma unroll
        for (int t = 0; t < 4; ++t) {
            float p = dist16(r0, r1, r2, r3, zr[t][0], zr[t][1], zr[t][2], zr[t][3]);
            p += __shfl_xor(p, 1);
            p += __shfl_xor(p, 2);
            // dist >= 0: float bits order-preserving; low 32 = row ->
            // first-occurrence tie-break like jnp.argmin.
            const unsigned long long key =
                ((unsigned long long)__float_as_uint(p) << 32) |
                (unsigned)(rowBase + k * 16);
            bestT[t] = u64min(bestT[t], key);
        }
    }
    #pragma unroll
    for (int t = 0; t < 4; ++t) {
        unsigned long long best = bestT[t];
        #pragma unroll
        for (int off = 32; off >= 4; off >>= 1)
            best = u64min(best, shfl_down_u64(best, off, 64));
        if (lane == 0) cand[t][w] = best;
    }
    __syncthreads();

    // ---- block reduce -> ws slots -> counter ----
    if (tid < 64) {
        const int t = tid >> 4, s = tid & 15;
        unsigned long long k = cand[t][s];
        #pragma unroll
        for (int off = 8; off > 0; off >>= 1)
            k = u64min(k, shfl_down_u64(k, off, 16));
        if (s == 0)
            atomicExch(&wsK[(bt * 4 + rt) * 8 + t], k);
        if (tid == 0) {
            __threadfence();
            const unsigned old = atomicAdd(&wsC[bt * 16], 1u);
            fin_s = ((old & 3u) == 3u);
        }
    }
    __syncthreads();
    if (!fin_s) return;

    // ================= finisher: 4 batches of this bt =================
    if (tid < 16) {                     // lane = rtIdx*4 + t
        unsigned long long k =
            atomicOr(&wsK[(bt * 4 + (tid >> 2)) * 8 + (tid & 3)], 0ull);
        k = u64min(k, shfl_down_u64(k, 8, 16));
        k = u64min(k, shfl_down_u64(k, 4, 16));
        if (tid < 4) nmin_s[tid] = (int)(k & 0xffffffffu);
    }
    // stage decoder weights (independent of nmin; all threads)
    {
        const float4* s4; float4* d4;
        s4 = (const float4*)w_d;  d4 = (float4*)L_wd;
        for (int i = tid; i < 1600; i += 1024) d4[i] = s4[i];
        s4 = (const float4*)w_d0; d4 = (float4*)L_wd0;
        for (int i = tid; i < 1500; i += 1024) d4[i] = s4[i];
        s4 = (const float4*)w_d1; d4 = (float4*)L_wd1;
        for (int i = tid; i < 450; i += 1024) d4[i] = s4[i];
        if (tid < 100) L_bd[tid]  = b_d[tid];
        if (tid < 60)  L_bd0[tid] = b_d0[tid];
        if (tid < 30)  { L_bd1[tid] = b_d1[tid]; L_wd2[tid] = w_d2[tid]; }
    }
    __syncthreads();

    // phase A: waves 8..11 -> batch i: z_e out, z_q, neighbors
    if (w >= 8 && w < 12) {
        const int i = w - 8;
        const int b = bt * 4 + i;
        const int nmin = nmin_s[i];
        const int nx = nmin >> 6, ny = nmin & 63;
        const int j = lane;
        out[b * 64 + j] = zs[i][j];                       // z_e
        const float zq = emb[nmin * 64 + j];
        zq_s[i][j] = zq;
        out[16384 + b * 64 + j] = zq;                     // z_q
        const int nb = 32768 + b * 320;                   // z_q_neighbors [B,5,64]
        out[nb + j] = zq;                                 // row 0: z_q
        float up = (nx < 63) ? emb[((nx + 1) * 64 + ny) * 64 + j] : 0.f;
        out[nb + 64 + j] = up;                            // row 1: up
        float dn = (nx > 0) ? emb[((nx - 1) * 64 + ny) * 64 + j] : 0.f;
        out[nb + 128 + j] = dn;                           // row 2: down
        out[nb + 192 + j] = 0.f;                          // row 3: right (faithful bug)
        float lf = (ny > 0) ? emb[(nx * 64 + (ny - 1)) * 64 + j] : 0.f;
        out[nb + 256 + j] = lf;                           // row 4: left
    }
    __syncthreads();

    // decode: waves 0..7 -> batch i = w>>1, input sel = w&1 (0=z_e, 1=z_q)
    const int di  = w >> 1;
    const int sel = w & 1;
    const bool dec = (w < 8);
    const float* zv = sel ? zq_s[di] : zs[di];

    if (dec) {
        for (int jj = lane; jj < 100; jj += 64) {
            float acc = L_bd[jj];
            for (int i = 0; i < 64; ++i)
                acc = fmaf(zv[i], L_wd[i * 100 + jj], acc);
            t0s[di][sel][jj] = lrelu(acc);
        }
    }
    __syncthreads();
    if (dec && lane < 60) {
        float acc = L_bd0[lane];
        for (int i = 0; i < 100; ++i)
            acc = fmaf(t0s[di][sel][i], L_wd0[i * 60 + lane], acc);
        t1s[di][sel][lane] = lrelu(acc);
    }
    __syncthreads();
    if (dec && lane < 30) {
        float acc = L_bd1[lane];
        for (int i = 0; i < 60; ++i)
            acc = fmaf(t1s[di][sel][i], L_wd1[i * 30 + lane], acc);
        t2s[di][sel][lane] = lrelu(acc);
    }
    __syncthreads();
    if (dec && lane == 0) {
        float acc = b_d2[0];
        for (int i = 0; i < 30; ++i)
            acc = fmaf(t2s[di][sel][i], L_wd2[i], acc);
        const float r = lrelu(acc);
        out[(sel ? 114944 : 114688) + bt * 4 + di] = r;   // decoder_q / decoder_e
    }
}

extern "C" void kernel_launch(void* const* d_in, const int* in_sizes, int n_in,
                              void* d_out, int out_size, void* d_ws, size_t ws_size,
                              hipStream_t stream) {
    (void)in_sizes; (void)n_in; (void)ws_size; (void)out_size;
    const float* x    = (const float*)d_in[0];
    const float* eps  = (const float*)d_in[1];
    const float* emb  = (const float*)d_in[2];
    const float* w_e0 = (const float*)d_in[3];
    const float* b_e0 = (const float*)d_in[4];
    const float* w_e1 = (const float*)d_in[5];
    const float* b_e1 = (const float*)d_in[6];
    const float* w_mu = (const float*)d_in[7];
    const float* b_mu = (const float*)d_in[8];
    const float* w_lv = (const float*)d_in[9];
    const float* b_lv = (const float*)d_in[10];
    const float* w_d  = (const float*)d_in[11];
    const float* b_d  = (const float*)d_in[12];
    const float* w_d0 = (const float*)d_in[13];
    const float* b_d0 = (const float*)d_in[14];
    const float* w_d1 = (const float*)d_in[15];
    const float* b_d1 = (const float*)d_in[16];
    const float* w_d2 = (const float*)d_in[17];
    const float* b_d2 = (const float*)d_in[18];
    float* out = (float*)d_out;
    unsigned long long* wsK = (unsigned long long*)d_ws;            // 16 KB
    unsigned int* wsC = (unsigned int*)((char*)d_ws + 65536);       // 64 counters, 64B stride

    vae_mega<<<256, 1024, 0, stream>>>(
        x, eps, emb, w_e0, b_e0, w_e1, b_e1, w_mu, b_mu, w_lv, b_lv,
        w_d, b_d, w_d0, b_d0, w_d1, b_d1, w_d2, b_d2, out, wsK, wsC);
}